// Round 9
// baseline (431.234 us; speedup 1.0000x reference)
//
#include <hip/hip_runtime.h>

#define B_TOT 4096
#define T_STEPS 512
#define IN 20
#define HID 51

typedef float f32x4 __attribute__((ext_vector_type(4)));
typedef short s16x8 __attribute__((ext_vector_type(8)));

__device__ __forceinline__ unsigned short f2bf(float f) {
    unsigned int u = __float_as_uint(f);
    unsigned int r = (u + 0x7fffu + ((u >> 16) & 1u)) >> 16;
    return (unsigned short)r;
}

#define L2E  1.4426950408889634f
#define L2E2 2.8853900817779268f

__device__ __forceinline__ float fast_rcp(float x) { return __builtin_amdgcn_rcpf(x); }
__device__ __forceinline__ float ex2(float x)      { return __builtin_amdgcn_exp2f(x); }
// sigma(x) where p = -x*log2(e) was folded into the weights
__device__ __forceinline__ float sig_p(float p)  { return fast_rcp(1.0f + ex2(p)); }
// tanh(x) where q = 2x*log2(e) was folded into the weights
__device__ __forceinline__ float tanh_q(float q) { return 1.0f - 2.0f * fast_rcp(1.0f + ex2(q)); }
// L2E2 * tanh(x), same folded argument — keeps cell state pre-scaled (C = L2E2*c)
__device__ __forceinline__ float tanh2_q(float q) {
    return __builtin_fmaf(fast_rcp(1.0f + ex2(q)), -2.0f * L2E2, L2E2);
}

// 14 waves (block 896), ONE tile per wave, 16 batches/block, grid = 256.
// r7 changes vs r6:
//  - L2 tile folded into tile 12's pad rows (unit 51 = 4 dead M-rows hold the
//    4 Wih2 gate rows). Wave 14 eliminated; its 2 ds_reads + 2 MFMAs come free
//    with tile 12's existing ones. Lanes 48..63 of the fat wave hold the L2
//    gates (i,f,g,o) for batch lane&15 in a[0..3].
//  - L2 scalar chain DEFERRED one step, into the post-barrier LDS-wait window
//    (it has no LDS dependence -> runs in otherwise-dead cycles).
//  - fat tile owned by wave 2 (SIMD {2,6,10} has only 3 waves -> balance);
//    wave 12 takes tile 2 in exchange.
//  - merged nonlinearity: 10 -> 7 trans/lane. C = (C1*Pi*Pg + L2E2(eg-1)*Pf)
//    * rcp(Pf*Pi*Pg); h = (ec-1) * rcp(Po*(1+ec)), ec = 2^min(C,126).
//   w0..w12: L1 tile (w2 <-> tile 12 swap), w13: x stager.
// Kept from r4/r6: x quad-buffer (no vmcnt drain at barrier), accx precompute
// (x-chunk MFMA off the critical path), compile-time buffer indices (x4 unroll).
// Weights/biases pre-scaled by -log2e (i,f,o) / 2*log2e (g); cell state kept
// pre-scaled (C = 2*log2e*c).

__global__ __launch_bounds__(896)
void lstm_fused(const float* __restrict__ x,
                const float* __restrict__ Wih1, const float* __restrict__ Whh1,
                const float* __restrict__ bih1, const float* __restrict__ bhh1,
                const float* __restrict__ Wih2, const float* __restrict__ Whh2,
                const float* __restrict__ bih2, const float* __restrict__ bhh2,
                const float* __restrict__ Wmu,  const float* __restrict__ bmu,
                const float* __restrict__ Wlv,  const float* __restrict__ blv,
                float* __restrict__ out)
{
    // h staging: [buf][chunk(c=0:k32..63,c=1:k64..95)][(((k>>3)&3)<<4)|batch][k&7]
    __shared__ __align__(16) unsigned short vA[2][2][64][8];
    // x staging, quad-buffered: slot t%4 holds x_t fragments (rows 48..63 stay 0)
    __shared__ __align__(16) unsigned short xS[4][64][8];

    const int tid  = threadIdx.x;
    const int lane = tid & 63;
    const int w    = tid >> 6;      // 0..13
    const int bidx = blockIdx.x;

    const int  tile  = (w == 2) ? 12 : (w == 12) ? 2 : w;
    const bool isT   = (w <= 12);   // L1 tile wave
    const bool isFAT = (w == 2);    // owns tile 12: units 48..50 + L2 rows 12..15
    const bool isST  = (w == 13);   // x stager

    // ---- gather A-operand weight fragments: A[m=lane&15][k=(lane>>4)*8+j] ----
    s16x8 wfrag[3];
    f32x4 binit = {0.f, 0.f, 0.f, 0.f};
    {
        const int m = lane & 15;
        #pragma unroll
        for (int ks = 0; ks < 3; ++ks) {
            s16x8 f;
            #pragma unroll
            for (int j = 0; j < 8; ++j) {
                int k = ks * 32 + ((lane >> 4) << 3) + j;
                float v = 0.0f;
                if (isT) {
                    if (isFAT && m >= 12) {
                        // L2 gate rows: A[k] = Wih2[g2][k-32] (no x part, k<32 -> 0)
                        int g2 = m - 12;
                        if (k >= 32 && k < 32 + HID)
                            v = Wih2[g2 * HID + (k - 32)] * ((g2 == 2) ? L2E2 : -L2E);
                    } else {
                        int g = m & 3, unit = tile * 4 + (m >> 2);
                        if (unit < HID) {
                            int row = g * HID + unit;
                            if (k < IN) v = Wih1[row * IN + k];
                            else if (k >= 32 && k < 32 + HID) v = Whh1[row * HID + (k - 32)];
                            v *= (g == 2) ? L2E2 : -L2E;
                        }
                    }
                }
                f[j] = (short)f2bf(v);
            }
            wfrag[ks] = f;
        }
        if (isT) {
            if (isFAT && (lane >> 4) == 3) {
                #pragma unroll
                for (int r = 0; r < 4; ++r)
                    binit[r] = (bih2[r] + bhh2[r]) * ((r == 2) ? L2E2 : -L2E);
            } else {
                int unit = tile * 4 + (lane >> 4);
                if (unit < HID) {
                    #pragma unroll
                    for (int r = 0; r < 4; ++r)
                        binit[r] = (bih1[r * HID + unit] + bhh1[r * HID + unit]) * ((r == 2) ? L2E2 : -L2E);
                }
            }
        }
    }

    float whh2g[4] = {0.f, 0.f, 0.f, 0.f};
    if (isFAT) {
        #pragma unroll
        for (int r = 0; r < 4; ++r) whh2g[r] = Whh2[r] * ((r == 2) ? L2E2 : -L2E);
    }

    // ---- h-write address (loop-invariant; fat wave's hi lanes masked off) ----
    int hchunk = 0, hrow = 0, hj = 0;
    if (isT) {
        int unit = tile * 4 + (lane >> 4);
        int k    = 32 + unit;
        hchunk = (k >> 5) - 1;
        hrow   = (((k >> 3) & 3) << 4) + (lane & 15);
        hj     = k & 7;
    }

    // ---- x stager setup (w13): 5 elems/lane, e = i*64+lane (320 total, no mask) ----
    const float* sp[5];
    int srow[5], sj[5];
    if (isST) {
        #pragma unroll
        for (int i = 0; i < 5; ++i) {
            int e = i * 64 + lane;
            int b = e / IN, m = e % IN;
            sp[i]   = x + ((size_t)(bidx * 16 + b) * T_STEPS) * IN + m;
            srow[i] = ((m >> 3) & 3) * 16 + b;
            sj[i]   = m & 7;
        }
    }

    // ---- zero-init staging buffers (pads must stay exact 0 forever) ----
    {
        unsigned short* vz = &vA[0][0][0][0];
        for (int i = tid; i < 2 * 2 * 64 * 8; i += 896) vz[i] = 0;
        unsigned short* xz = &xS[0][0][0];
        for (int i = tid; i < 4 * 64 * 8; i += 896) xz[i] = 0;
    }
    __syncthreads();
    float rE[5], rO[5];
    if (isST) {
        #pragma unroll
        for (int i = 0; i < 5; ++i) {
            xS[0][srow[i]][sj[i]] = f2bf(sp[i][0]);          // x_0
            xS[1][srow[i]][sj[i]] = f2bf(sp[i][IN]);         // x_1
            rE[i] = sp[i][(size_t)2 * IN];                   // x_2 (write at t=0)
            rO[i] = sp[i][(size_t)3 * IN];                   // x_3 (write at t=1)
        }
    }
    __syncthreads();

    // ---- precompute accx (x-chunk MFMA) for step 0 from xS[0] ----
    f32x4 accx = {0.f, 0.f, 0.f, 0.f};
    if (isT) {
        const s16x8 b00 = *(const s16x8*)&xS[0][lane][0];
        accx = __builtin_amdgcn_mfma_f32_16x16x32_bf16(wfrag[0], b00, binit, 0, 0, 0);
    }

    float C1t = 0.f;                // pre-scaled cell state: C = 2*log2e*c
    float C2p = 0.f, h2p = 0.f, sum2 = 0.f;
    f32x4 aP = {0.f, 0.f, 0.f, 0.f};  // deferred L2 gates (fat wave, lanes 48..63)

    // One timestep. P = tt&1 (h buffer), XR = (tt+1)%4 (x for next step),
    // XW = (tt+2)%4 (x slot written this step), XREG = rE (even tt) / rO (odd).
#define STEP(tt, P, XR, XW, XREG)                                                \
    {                                                                            \
        if (isST) {                                                              \
            const int t4 = ((tt) < T_STEPS - 4) ? (tt) + 4 : T_STEPS - 1;        \
            _Pragma("unroll")                                                    \
            for (int i = 0; i < 5; ++i) {                                        \
                xS[XW][srow[i]][sj[i]] = f2bf(XREG[i]);                          \
                XREG[i] = sp[i][(size_t)t4 * IN];                                \
            }                                                                    \
        }                                                                        \
        if (isT) {                                                               \
            const s16x8 bf1  = *(const s16x8*)&vA[P][0][lane][0];                \
            const s16x8 bf2  = *(const s16x8*)&vA[P][1][lane][0];                \
            const s16x8 bf0n = *(const s16x8*)&xS[XR][lane][0];                  \
            /* deferred L2 chain (no LDS dep): fills the lgkmcnt wait window */  \
            if (isFAT && (tt) >= 2 && lane >= 48) {                              \
                float pi = aP[0] + whh2g[0] * h2p;                               \
                float pf = aP[1] + whh2g[1] * h2p;                               \
                float pg = aP[2] + whh2g[2] * h2p;                               \
                float po = aP[3] + whh2g[3] * h2p;                               \
                float C2 = sig_p(pf) * C2p + sig_p(pi) * tanh2_q(pg);            \
                C2p = C2;                                                        \
                h2p = sig_p(po) * tanh_q(C2);                                    \
                sum2 += h2p;                                                     \
            }                                                                    \
            f32x4 a = accx;                                                      \
            a = __builtin_amdgcn_mfma_f32_16x16x32_bf16(wfrag[1], bf1, a, 0, 0, 0); \
            a = __builtin_amdgcn_mfma_f32_16x16x32_bf16(wfrag[2], bf2, a, 0, 0, 0); \
            if (isFAT) aP = a;                                                   \
            /* merged nonlinearity: 5 exp2 + 2 rcp */                            \
            float ei = ex2(a[0]), ef = ex2(a[1]), eg = ex2(a[2]), eo = ex2(a[3]);\
            float Pi = 1.f + ei, Pf = 1.f + ef, Pg = 1.f + eg, Po = 1.f + eo;    \
            float Pig = Pi * Pg;                                                 \
            float rr  = fast_rcp(Pf * Pig);                                      \
            float C   = __builtin_fmaf(C1t, Pig, L2E2 * ((eg - 1.f) * Pf)) * rr; \
            C1t = C;                                                             \
            float ec  = ex2(fminf(C, 126.f));                                    \
            float h   = (ec - 1.f) * fast_rcp(Po * (1.f + ec));                  \
            if (!(isFAT && (lane >> 4) == 3))                                    \
                vA[(P) ^ 1][hchunk][hrow][hj] = f2bf(h);                         \
            accx = __builtin_amdgcn_mfma_f32_16x16x32_bf16(wfrag[0], bf0n, binit, 0, 0, 0); \
        }                                                                        \
        __syncthreads();                                                         \
    }

    for (int t = 0; t < T_STEPS; t += 4) {
        STEP(t + 0, 0, 1, 2, rE)
        STEP(t + 1, 1, 2, 3, rO)
        STEP(t + 2, 0, 3, 0, rE)
        STEP(t + 3, 1, 0, 1, rO)
    }
#undef STEP

    // ---- drain: aP_511 -> h2_510; then h1_511 (in vA[0]) -> h2_511 + head ----
    if (isFAT) {
        if (lane >= 48) {
            float pi = aP[0] + whh2g[0] * h2p;
            float pf = aP[1] + whh2g[1] * h2p;
            float pg = aP[2] + whh2g[2] * h2p;
            float po = aP[3] + whh2g[3] * h2p;
            float C2 = sig_p(pf) * C2p + sig_p(pi) * tanh2_q(pg);
            C2p = C2;
            h2p = sig_p(po) * tanh_q(C2);
            sum2 += h2p;
        }
        const s16x8 bf1 = *(const s16x8*)&vA[0][0][lane][0];
        const s16x8 bf2 = *(const s16x8*)&vA[0][1][lane][0];
        f32x4 a = accx;   // rows 12..15 = l2binit (x-weights are 0 there)
        a = __builtin_amdgcn_mfma_f32_16x16x32_bf16(wfrag[1], bf1, a, 0, 0, 0);
        a = __builtin_amdgcn_mfma_f32_16x16x32_bf16(wfrag[2], bf2, a, 0, 0, 0);
        if (lane >= 48) {
            float pi = a[0] + whh2g[0] * h2p;
            float pf = a[1] + whh2g[1] * h2p;
            float pg = a[2] + whh2g[2] * h2p;
            float po = a[3] + whh2g[3] * h2p;
            float C2 = sig_p(pf) * C2p + sig_p(pi) * tanh2_q(pg);
            h2p = sig_p(po) * tanh_q(C2);
            sum2 += h2p;

            // ---- head: (lower, mu, upper, log_var) ----
            float agg = sum2 * (1.0f / 512.0f);
            float mu  = Wmu[0] * agg + bmu[0];
            float lv  = Wlv[0] * agg + blv[0];
            float sg  = __expf(0.5f * lv);
            int bg = bidx * 16 + (lane & 15);
            out[bg]             = mu - 1.96f * sg;
            out[B_TOT + bg]     = mu;
            out[2 * B_TOT + bg] = mu + 1.96f * sg;
            out[3 * B_TOT + bg] = lv;
        }
    }
}

extern "C" void kernel_launch(void* const* d_in, const int* in_sizes, int n_in,
                              void* d_out, int out_size, void* d_ws, size_t ws_size,
                              hipStream_t stream) {
    const float* x    = (const float*)d_in[0];
    const float* Wih1 = (const float*)d_in[1];
    const float* Whh1 = (const float*)d_in[2];
    const float* bih1 = (const float*)d_in[3];
    const float* bhh1 = (const float*)d_in[4];
    const float* Wih2 = (const float*)d_in[5];
    const float* Whh2 = (const float*)d_in[6];
    const float* bih2 = (const float*)d_in[7];
    const float* bhh2 = (const float*)d_in[8];
    const float* Wmu  = (const float*)d_in[9];
    const float* bmu  = (const float*)d_in[10];
    const float* Wlv  = (const float*)d_in[11];
    const float* blv  = (const float*)d_in[12];
    float* out = (float*)d_out;

    lstm_fused<<<dim3(B_TOT / 16), dim3(896), 0, stream>>>(
        x, Wih1, Whh1, bih1, bhh1, Wih2, Whh2, bih2, bhh2, Wmu, bmu, Wlv, blv, out);
}